// Round 13
// baseline (558.074 us; speedup 1.0000x reference)
//
#include <hip/hip_runtime.h>

#define NN 200000
#define EE 400000
#define GG 4096

// ws layout (float offsets)
#define AGG_OFF 0
#define H1_OFF  (NN * 64)                  // 12,800,000
#define SE_OFF  (H1_OFF + NN * 64)         // 25,600,000 (2*GG ints)
#define GSUM_OFF (SE_OFF + 2 * GG)         // per-graph H2 sums (GG*128 floats)
#define CSR_OFF (GSUM_OFF + GG * 128)      // CSR + permuted edges; never clobbered

#define NB1 ((NN + 1023) / 1024)           // 196 scan blocks

// ---------------- segment boundaries from sorted batch ----------------
__global__ void bounds_kernel(const int* __restrict__ batch, int* __restrict__ se) {
    int n = blockIdx.x * blockDim.x + threadIdx.x;
    if (n >= NN) return;
    int b = batch[n];
    if (n == 0 || batch[n - 1] != b) se[b] = n;                 // start
    if (n == NN - 1 || batch[n + 1] != b) se[GG + b] = n + 1;   // end
}

// ---------------- CSR build ----------------
__global__ void deg_kernel(const int* __restrict__ ei, int* __restrict__ cursor) {
    int e = blockIdx.x * blockDim.x + threadIdx.x;
    if (e >= EE) return;
    atomicAdd(cursor + ei[EE + e], 1);
}

__global__ __launch_bounds__(256) void scan1_kernel(const int* __restrict__ deg,
                                                    int* __restrict__ rowptr,
                                                    int* __restrict__ partials) {
    __shared__ int sdata[256];
    int t = threadIdx.x;
    int base = blockIdx.x * 1024 + t * 4;
    int v[4]; int s = 0;
#pragma unroll
    for (int j = 0; j < 4; j++) {
        v[j] = (base + j < NN) ? deg[base + j] : 0;
        s += v[j];
    }
    sdata[t] = s;
    __syncthreads();
#pragma unroll
    for (int off = 1; off < 256; off <<= 1) {
        int x = (t >= off) ? sdata[t - off] : 0;
        __syncthreads();
        sdata[t] += x;
        __syncthreads();
    }
    int run = sdata[t] - s;
#pragma unroll
    for (int j = 0; j < 4; j++) {
        if (base + j < NN) rowptr[base + j] = run;
        run += v[j];
    }
    if (t == 255) partials[blockIdx.x] = sdata[255];
}

__global__ __launch_bounds__(256) void scan2_kernel(int* __restrict__ partials) {
    __shared__ int sdata[256];
    int t = threadIdx.x;
    int p = (t < NB1) ? partials[t] : 0;
    sdata[t] = p;
    __syncthreads();
#pragma unroll
    for (int off = 1; off < 256; off <<= 1) {
        int x = (t >= off) ? sdata[t - off] : 0;
        __syncthreads();
        sdata[t] += x;
        __syncthreads();
    }
    if (t < NB1) partials[t] = sdata[t] - p;
}

__global__ __launch_bounds__(256) void scan3_kernel(int* __restrict__ rowptr,
                                                    const int* __restrict__ partials) {
    int t = threadIdx.x;
    int add = partials[blockIdx.x];
    int base = blockIdx.x * 1024 + t * 4;
#pragma unroll
    for (int j = 0; j < 4; j++)
        if (base + j < NN) rowptr[base + j] += add;
}

__global__ void scatter_kernel(const int* __restrict__ ei,
                               const int* __restrict__ rowptr,
                               int* __restrict__ cursor,
                               int* __restrict__ eidx,
                               int* __restrict__ esrc) {
    int e = blockIdx.x * blockDim.x + threadIdx.x;
    if (e >= EE) return;
    int d = ei[EE + e];
    int pos = rowptr[d] + atomicAdd(cursor + d, 1);
    eidx[pos] = e;
    esrc[pos] = ei[e];
}

// permute edge attrs into slot order: eaperm[p] = ea[eidx[p]]
__global__ __launch_bounds__(256) void permute_kernel(const float* __restrict__ ea,
                                                      const int* __restrict__ eidx,
                                                      float* __restrict__ eaperm) {
    int p4 = blockIdx.x * 16 + (threadIdx.x >> 4);
    if (p4 >= EE) return;
    int elem = threadIdx.x & 15;
    int e = eidx[p4];
    eaperm[(size_t)p4 * 16 + elem] = ea[(size_t)e * 16 + elem];
}

// ---------------- gather aggregation (layer 1; 2-edge guarded, R11 form) -----
__global__ __launch_bounds__(256) void agg_pass(const float* __restrict__ xin,
                                                const float* __restrict__ eaperm,
                                                const int* __restrict__ esrc,
                                                const float* __restrict__ ew,
                                                const float* __restrict__ eb,
                                                const int* __restrict__ rowptr,
                                                const int* __restrict__ cnt,
                                                float* __restrict__ agg) {
    const int lane = threadIdx.x & 63;
    int n = blockIdx.x * 4 + (threadIdx.x >> 6);
    if (n >= NN) return;

    float Wr[16];
#pragma unroll
    for (int k = 0; k < 16; k++) Wr[k] = ew[k * 64 + lane];
    const float br = eb[lane];

    int s   = __builtin_amdgcn_readfirstlane(rowptr[n]);
    int deg = __builtin_amdgcn_readfirstlane(cnt[n]);

    float sum = xin[(size_t)n * 64 + lane];

    for (int i = 0; i < deg; i += 2) {
        const bool two = (i + 1 < deg);
        const int p0 = s + i, p1 = s + i + 1;
        int s0 = esrc[p0];
        int s1 = two ? esrc[p1] : s0;
        const float4* q0 = (const float4*)(eaperm + (size_t)p0 * 16);
        const float4* q1 = (const float4*)(eaperm + (size_t)p1 * 16);
        float4 A0 = q0[0], A1 = q0[1], A2 = q0[2], A3 = q0[3];
        float4 B0, B1, B2, B3;
        if (two) { B0 = q1[0]; B1 = q1[1]; B2 = q1[2]; B3 = q1[3]; }
        float xv0 = xin[(size_t)s0 * 64 + lane];
        float xv1 = two ? xin[(size_t)s1 * 64 + lane] : 0.0f;

        float acc0 = br;
        acc0 += A0.x * Wr[0];  acc0 += A0.y * Wr[1];
        acc0 += A0.z * Wr[2];  acc0 += A0.w * Wr[3];
        acc0 += A1.x * Wr[4];  acc0 += A1.y * Wr[5];
        acc0 += A1.z * Wr[6];  acc0 += A1.w * Wr[7];
        acc0 += A2.x * Wr[8];  acc0 += A2.y * Wr[9];
        acc0 += A2.z * Wr[10]; acc0 += A2.w * Wr[11];
        acc0 += A3.x * Wr[12]; acc0 += A3.y * Wr[13];
        acc0 += A3.z * Wr[14]; acc0 += A3.w * Wr[15];
        sum += fmaxf(acc0 + xv0, 0.0f);
        if (two) {
            float acc1 = br;
            acc1 += B0.x * Wr[0];  acc1 += B0.y * Wr[1];
            acc1 += B0.z * Wr[2];  acc1 += B0.w * Wr[3];
            acc1 += B1.x * Wr[4];  acc1 += B1.y * Wr[5];
            acc1 += B1.z * Wr[6];  acc1 += B1.w * Wr[7];
            acc1 += B2.x * Wr[8];  acc1 += B2.y * Wr[9];
            acc1 += B2.z * Wr[10]; acc1 += B2.w * Wr[11];
            acc1 += B3.x * Wr[12]; acc1 += B3.y * Wr[13];
            acc1 += B3.z * Wr[14]; acc1 += B3.w * Wr[15];
            sum += fmaxf(acc1 + xv1, 0.0f);
        }
    }
    agg[(size_t)n * 64 + lane] = sum;
}

// ---------------- fused node-1 MLP: Y = relu( relu(X@W1+b1) @ W2 + b2 ) ------
__global__ __launch_bounds__(256) void node1_fused(const float* __restrict__ X,
                                                   const float* __restrict__ W1,
                                                   const float* __restrict__ B1,
                                                   const float* __restrict__ W2,
                                                   const float* __restrict__ B2,
                                                   float* __restrict__ Y,
                                                   int rows) {
    __shared__ float W1s[64 * 64];
    __shared__ float W2s[64 * 64];
    __shared__ float Hs[64 * 68];

    {
        const float4* s1 = (const float4*)W1;
        const float4* s2 = (const float4*)W2;
        float4* d1 = (float4*)W1s;
        float4* d2 = (float4*)W2s;
        for (int i = threadIdx.x; i < 1024; i += 256) { d1[i] = s1[i]; d2[i] = s2[i]; }
    }

    const int cg = threadIdx.x % 8;
    const int rg = threadIdx.x / 8;
    const int c0a = cg * 4, c0b = 32 + cg * 4;
    const int rbase = blockIdx.x * 64 + rg * 2;

    const float* xptr[2];
#pragma unroll
    for (int r = 0; r < 2; r++) {
        int rr = rbase + r;
        int ri = (rr < rows) ? rr : (rows - 1);
        xptr[r] = X + (size_t)ri * 64;
    }

    float acc[2][8];
    {
        const float4 v0 = *(const float4*)(B1 + c0a);
        const float4 v1 = *(const float4*)(B1 + c0b);
#pragma unroll
        for (int r = 0; r < 2; r++) {
            acc[r][0] = v0.x; acc[r][1] = v0.y; acc[r][2] = v0.z; acc[r][3] = v0.w;
            acc[r][4] = v1.x; acc[r][5] = v1.y; acc[r][6] = v1.z; acc[r][7] = v1.w;
        }
    }

    float4 a_cur[2], a_nxt[2];
#pragma unroll
    for (int r = 0; r < 2; r++) a_cur[r] = *(const float4*)(xptr[r]);

    __syncthreads();

#pragma unroll 2
    for (int k4 = 0; k4 < 64; k4 += 4) {
        if (k4 + 4 < 64) {
#pragma unroll
            for (int r = 0; r < 2; r++) a_nxt[r] = *(const float4*)(xptr[r] + k4 + 4);
        }
#pragma unroll
        for (int kk = 0; kk < 4; kk++) {
            const float4 w0 = *(const float4*)(W1s + (k4 + kk) * 64 + c0a);
            const float4 w1 = *(const float4*)(W1s + (k4 + kk) * 64 + c0b);
#pragma unroll
            for (int r = 0; r < 2; r++) {
                float av = (kk == 0) ? a_cur[r].x : (kk == 1) ? a_cur[r].y
                         : (kk == 2) ? a_cur[r].z : a_cur[r].w;
                acc[r][0] += av * w0.x; acc[r][1] += av * w0.y;
                acc[r][2] += av * w0.z; acc[r][3] += av * w0.w;
                acc[r][4] += av * w1.x; acc[r][5] += av * w1.y;
                acc[r][6] += av * w1.z; acc[r][7] += av * w1.w;
            }
        }
#pragma unroll
        for (int r = 0; r < 2; r++) a_cur[r] = a_nxt[r];
    }

#pragma unroll
    for (int r = 0; r < 2; r++) {
        const int lrow = rg * 2 + r;
        float4 v0, v1;
        v0.x = fmaxf(acc[r][0], 0.0f); v0.y = fmaxf(acc[r][1], 0.0f);
        v0.z = fmaxf(acc[r][2], 0.0f); v0.w = fmaxf(acc[r][3], 0.0f);
        v1.x = fmaxf(acc[r][4], 0.0f); v1.y = fmaxf(acc[r][5], 0.0f);
        v1.z = fmaxf(acc[r][6], 0.0f); v1.w = fmaxf(acc[r][7], 0.0f);
        *(float4*)(Hs + lrow * 68 + c0a) = v0;
        *(float4*)(Hs + lrow * 68 + c0b) = v1;
    }

    {
        const float4 v0 = *(const float4*)(B2 + c0a);
        const float4 v1 = *(const float4*)(B2 + c0b);
#pragma unroll
        for (int r = 0; r < 2; r++) {
            acc[r][0] = v0.x; acc[r][1] = v0.y; acc[r][2] = v0.z; acc[r][3] = v0.w;
            acc[r][4] = v1.x; acc[r][5] = v1.y; acc[r][6] = v1.z; acc[r][7] = v1.w;
        }
    }
    __syncthreads();

#pragma unroll 2
    for (int k4 = 0; k4 < 64; k4 += 4) {
        float4 a[2];
#pragma unroll
        for (int r = 0; r < 2; r++) a[r] = *(const float4*)(Hs + (rg * 2 + r) * 68 + k4);
#pragma unroll
        for (int kk = 0; kk < 4; kk++) {
            const float4 w0 = *(const float4*)(W2s + (k4 + kk) * 64 + c0a);
            const float4 w1 = *(const float4*)(W2s + (k4 + kk) * 64 + c0b);
#pragma unroll
            for (int r = 0; r < 2; r++) {
                float av = (kk == 0) ? a[r].x : (kk == 1) ? a[r].y
                         : (kk == 2) ? a[r].z : a[r].w;
                acc[r][0] += av * w0.x; acc[r][1] += av * w0.y;
                acc[r][2] += av * w0.z; acc[r][3] += av * w0.w;
                acc[r][4] += av * w1.x; acc[r][5] += av * w1.y;
                acc[r][6] += av * w1.z; acc[r][7] += av * w1.w;
            }
        }
    }

#pragma unroll
    for (int r = 0; r < 2; r++) {
        int rr = rbase + r;
        if (rr < rows) {
            float4 v0, v1;
            v0.x = fmaxf(acc[r][0], 0.0f); v0.y = fmaxf(acc[r][1], 0.0f);
            v0.z = fmaxf(acc[r][2], 0.0f); v0.w = fmaxf(acc[r][3], 0.0f);
            v1.x = fmaxf(acc[r][4], 0.0f); v1.y = fmaxf(acc[r][5], 0.0f);
            v1.z = fmaxf(acc[r][6], 0.0f); v1.w = fmaxf(acc[r][7], 0.0f);
            *(float4*)(Y + (size_t)rr * 64 + c0a) = v0;
            *(float4*)(Y + (size_t)rr * 64 + c0b) = v1;
        }
    }
}

// ---------------- FUSED layer-2: gather(agg) -> LDS -> GEMM(n2w1) -> pool ----
// Block = 64 nodes. Phase 1: 4 waves gather 16 nodes each into As (LDS, never
// HBM). Phase 2: GEMM rows from As against Bs(=n2w1 staged), relu, run-reduce
// into per-graph sums. Blocks at different phases overlap on a CU.
__global__ __launch_bounds__(256) void agg_gemm_pool(const float* __restrict__ xin,   // h1
                                                     const float* __restrict__ eaperm,
                                                     const int* __restrict__ esrc,
                                                     const float* __restrict__ ew,    // e2w
                                                     const float* __restrict__ eb,    // e2b
                                                     const int* __restrict__ rowptr,
                                                     const int* __restrict__ cnt,
                                                     const float* __restrict__ W,     // n2w1 64x128
                                                     const float* __restrict__ Bv,    // n2b1
                                                     const int* __restrict__ batch,
                                                     float* __restrict__ gsum,
                                                     int rows) {
    constexpr int K = 64, C = 128;
    constexpr int CPT = 8, RPT = 4, COLG = 16;

    __shared__ float Bs[K * C];        // 32 KB
    __shared__ float As[64 * 68];      // 17 KB (padded stride 68: 16B-aligned, <=2-way banks)
    __shared__ float pool[7 * C];      // 3.5 KB

    const int lane = threadIdx.x & 63;
    const int wid  = threadIdx.x >> 6;
    const int rowbase = blockIdx.x * 64;

    // stage W + zero pool (loads in flight during gather setup)
    {
        const float4* wsrc = (const float4*)W;
        float4* wdst = (float4*)Bs;
        for (int i = threadIdx.x; i < K * C / 4; i += 256) wdst[i] = wsrc[i];
    }
    for (int i = threadIdx.x; i < 7 * C; i += 256) pool[i] = 0.0f;

    // ---- phase 1: gather 16 nodes per wave into As ----
    float Wr[16];
#pragma unroll
    for (int k = 0; k < 16; k++) Wr[k] = ew[k * 64 + lane];
    const float br = eb[lane];

    // preload (start,deg) for all 16 nodes: 32 independent loads up-front
    int sArr[16], dArr[16];
#pragma unroll
    for (int j = 0; j < 16; j++) {
        int n = rowbase + wid * 16 + j;
        int nc = (n < rows) ? n : (rows - 1);
        sArr[j] = rowptr[nc];
        dArr[j] = (n < rows) ? cnt[nc] : 0;
    }

#pragma unroll 1
    for (int j = 0; j < 16; j++) {
        int lrow = wid * 16 + j;
        int n = rowbase + lrow;
        float sum = 0.0f;
        if (n < rows) {
            int s = sArr[j], deg = dArr[j];
            sum = xin[(size_t)n * 64 + lane];
            for (int i = 0; i < deg; i += 2) {
                const bool two = (i + 1 < deg);
                const int p0 = s + i, p1 = s + i + 1;
                int s0 = esrc[p0];
                int s1 = two ? esrc[p1] : s0;
                const float4* q0 = (const float4*)(eaperm + (size_t)p0 * 16);
                const float4* q1 = (const float4*)(eaperm + (size_t)p1 * 16);
                float4 A0 = q0[0], A1 = q0[1], A2 = q0[2], A3 = q0[3];
                float4 B0, B1, B2, B3;
                if (two) { B0 = q1[0]; B1 = q1[1]; B2 = q1[2]; B3 = q1[3]; }
                float xv0 = xin[(size_t)s0 * 64 + lane];
                float xv1 = two ? xin[(size_t)s1 * 64 + lane] : 0.0f;

                float acc0 = br;
                acc0 += A0.x * Wr[0];  acc0 += A0.y * Wr[1];
                acc0 += A0.z * Wr[2];  acc0 += A0.w * Wr[3];
                acc0 += A1.x * Wr[4];  acc0 += A1.y * Wr[5];
                acc0 += A1.z * Wr[6];  acc0 += A1.w * Wr[7];
                acc0 += A2.x * Wr[8];  acc0 += A2.y * Wr[9];
                acc0 += A2.z * Wr[10]; acc0 += A2.w * Wr[11];
                acc0 += A3.x * Wr[12]; acc0 += A3.y * Wr[13];
                acc0 += A3.z * Wr[14]; acc0 += A3.w * Wr[15];
                sum += fmaxf(acc0 + xv0, 0.0f);
                if (two) {
                    float acc1 = br;
                    acc1 += B0.x * Wr[0];  acc1 += B0.y * Wr[1];
                    acc1 += B0.z * Wr[2];  acc1 += B0.w * Wr[3];
                    acc1 += B1.x * Wr[4];  acc1 += B1.y * Wr[5];
                    acc1 += B1.z * Wr[6];  acc1 += B1.w * Wr[7];
                    acc1 += B2.x * Wr[8];  acc1 += B2.y * Wr[9];
                    acc1 += B2.z * Wr[10]; acc1 += B2.w * Wr[11];
                    acc1 += B3.x * Wr[12]; acc1 += B3.y * Wr[13];
                    acc1 += B3.z * Wr[14]; acc1 += B3.w * Wr[15];
                    sum += fmaxf(acc1 + xv1, 0.0f);
                }
            }
        }
        As[lrow * 68 + lane] = sum;
    }

    __syncthreads();   // As complete, Bs staged

    // ---- phase 2: GEMM from LDS + relu + pooled reduction ----
    const int cg = threadIdx.x % COLG;
    const int rg = threadIdx.x / COLG;      // 0..15
    const int c0a = cg * 4;
    const int c0b = 64 + cg * 4;
    const int lr0 = rg * RPT;

    float acc[RPT][CPT];
    {
        const float4 v0 = *(const float4*)(Bv + c0a);
        const float4 v1 = *(const float4*)(Bv + c0b);
#pragma unroll
        for (int r = 0; r < RPT; r++) {
            acc[r][0] = v0.x; acc[r][1] = v0.y; acc[r][2] = v0.z; acc[r][3] = v0.w;
            acc[r][4] = v1.x; acc[r][5] = v1.y; acc[r][6] = v1.z; acc[r][7] = v1.w;
        }
    }

#pragma unroll 2
    for (int k4 = 0; k4 < K; k4 += 4) {
        float4 a[RPT];
#pragma unroll
        for (int r = 0; r < RPT; r++)
            a[r] = *(const float4*)(As + (lr0 + r) * 68 + k4);
#pragma unroll
        for (int kk = 0; kk < 4; kk++) {
            const float4 w0 = *(const float4*)(Bs + (k4 + kk) * C + c0a);
            const float4 w1 = *(const float4*)(Bs + (k4 + kk) * C + c0b);
#pragma unroll
            for (int r = 0; r < RPT; r++) {
                float av = (kk == 0) ? a[r].x : (kk == 1) ? a[r].y
                         : (kk == 2) ? a[r].z : a[r].w;
                acc[r][0] += av * w0.x; acc[r][1] += av * w0.y;
                acc[r][2] += av * w0.z; acc[r][3] += av * w0.w;
                acc[r][4] += av * w1.x; acc[r][5] += av * w1.y;
                acc[r][6] += av * w1.z; acc[r][7] += av * w1.w;
            }
        }
    }

    int r0c = rowbase; if (r0c > rows - 1) r0c = rows - 1;
    int r1c = rowbase + 63; if (r1c > rows - 1) r1c = rows - 1;
    const int gfirst = batch[r0c];
    const int glast  = batch[r1c];
    const int span = glast - gfirst + 1;
    const bool useLds = (span <= 7);

    float part[CPT];
    int curg = -1;
#pragma unroll 1
    for (int r = 0; r < RPT; r++) {
        int rr = rowbase + lr0 + r;
        if (rr >= rows) break;
        int g = batch[rr];
        if (g != curg) {
            if (curg >= 0) {
                float* p = useLds ? (pool + (curg - gfirst) * C)
                                  : (gsum + (size_t)curg * C);
#pragma unroll
                for (int j = 0; j < 4; j++) atomicAdd(p + c0a + j, part[j]);
#pragma unroll
                for (int j = 0; j < 4; j++) atomicAdd(p + c0b + j, part[4 + j]);
            }
            curg = g;
#pragma unroll
            for (int j = 0; j < CPT; j++) part[j] = 0.0f;
        }
#pragma unroll
        for (int j = 0; j < CPT; j++) part[j] += fmaxf(acc[r][j], 0.0f);
    }
    if (curg >= 0) {
        float* p = useLds ? (pool + (curg - gfirst) * C)
                          : (gsum + (size_t)curg * C);
#pragma unroll
        for (int j = 0; j < 4; j++) atomicAdd(p + c0a + j, part[j]);
#pragma unroll
        for (int j = 0; j < 4; j++) atomicAdd(p + c0b + j, part[4 + j]);
    }

    if (useLds) {
        __syncthreads();
        for (int i = threadIdx.x; i < span * C; i += 256) {
            float v = pool[i];
            if (v != 0.0f)
                atomicAdd(gsum + (size_t)(gfirst + (i >> 7)) * C + (i & 127), v);
        }
    }
}

// ---------------- head: m = gsum/cnt, emb = m@W2+b2 (commuted), 5-layer MLP ----
__global__ __launch_bounds__(128) void head_kernel(const float* __restrict__ gsum,
                                                   const int* __restrict__ se,
                                                   const float* __restrict__ usr,
                                                   const float* __restrict__ w2, const float* __restrict__ b2,
                                                   const float* __restrict__ h1w, const float* __restrict__ h1b,
                                                   const float* __restrict__ h2w, const float* __restrict__ h2b,
                                                   const float* __restrict__ h3w, const float* __restrict__ h3b,
                                                   const float* __restrict__ h4w, const float* __restrict__ h4b,
                                                   const float* __restrict__ h5w, const float* __restrict__ h5b,
                                                   float* __restrict__ out) {
    int g = blockIdx.x;
    int c = threadIdx.x;
    __shared__ float m[128];
    __shared__ float z0[140];
    __shared__ float z1[128];
    __shared__ float z2[64];
    __shared__ float z3[32];
    __shared__ float z4[16];

    int s = se[g], e = se[GG + g];
    float cnt = fmaxf((float)(e - s), 1.0f);
    m[c] = gsum[(size_t)g * 128 + c] / cnt;
    __syncthreads();

    {
        float acc = b2[c];
        for (int k = 0; k < 128; k++) acc += m[k] * w2[k * 128 + c];
        z0[c] = (e > s) ? acc : 0.0f;
    }
    if (c < 12) z0[128 + c] = usr[g * 12 + c];
    __syncthreads();

    {
        float acc = h1b[c];
        for (int k = 0; k < 140; k++) acc += z0[k] * h1w[k * 128 + c];
        z1[c] = fmaxf(acc, 0.0f);
    }
    __syncthreads();
    if (c < 64) {
        float acc = h2b[c];
        for (int k = 0; k < 128; k++) acc += z1[k] * h2w[k * 64 + c];
        z2[c] = fmaxf(acc, 0.0f);
    }
    __syncthreads();
    if (c < 32) {
        float acc = h3b[c];
        for (int k = 0; k < 64; k++) acc += z2[k] * h3w[k * 32 + c];
        z3[c] = fmaxf(acc, 0.0f);
    }
    __syncthreads();
    if (c < 16) {
        float acc = h4b[c];
        for (int k = 0; k < 32; k++) acc += z3[k] * h4w[k * 16 + c];
        z4[c] = fmaxf(acc, 0.0f);
    }
    __syncthreads();
    if (c == 0) {
        float acc = h5b[0];
        for (int k = 0; k < 16; k++) acc += z4[k] * h5w[k];
        out[g] = acc;
    }
}

extern "C" void kernel_launch(void* const* d_in, const int* in_sizes, int n_in,
                              void* d_out, int out_size, void* d_ws, size_t ws_size,
                              hipStream_t stream) {
    const float* x    = (const float*)d_in[0];
    const int*   ei   = (const int*)d_in[1];
    const float* ea   = (const float*)d_in[2];
    const int*   batch= (const int*)d_in[3];
    const float* usr  = (const float*)d_in[4];
    const float* e1w  = (const float*)d_in[5],  *e1b  = (const float*)d_in[6];
    const float* n1w1 = (const float*)d_in[7],  *n1b1 = (const float*)d_in[8];
    const float* n1w2 = (const float*)d_in[9],  *n1b2 = (const float*)d_in[10];
    const float* e2w  = (const float*)d_in[11], *e2b  = (const float*)d_in[12];
    const float* n2w1 = (const float*)d_in[13], *n2b1 = (const float*)d_in[14];
    const float* n2w2 = (const float*)d_in[15], *n2b2 = (const float*)d_in[16];
    const float* h1w  = (const float*)d_in[17], *h1b  = (const float*)d_in[18];
    const float* h2w  = (const float*)d_in[19], *h2b  = (const float*)d_in[20];
    const float* h3w  = (const float*)d_in[21], *h3b  = (const float*)d_in[22];
    const float* h4w  = (const float*)d_in[23], *h4b  = (const float*)d_in[24];
    const float* h5w  = (const float*)d_in[25], *h5b  = (const float*)d_in[26];

    float* w    = (float*)d_ws;
    float* agg  = w + AGG_OFF;
    float* h1   = w + H1_OFF;
    int*   se   = (int*)(w + SE_OFF);
    float* gsum = w + GSUM_OFF;

    int*   rowptr   = (int*)(w + CSR_OFF);
    int*   cursor   = rowptr + NN;
    int*   eidx     = cursor + NN;
    int*   esrc     = eidx + EE;
    int*   partials = esrc + EE;
    float* eaperm   = (float*)(partials + 256);

    hipMemsetAsync(se, 0, (size_t)GG * 2 * sizeof(int), stream);
    hipMemsetAsync(cursor, 0, (size_t)NN * sizeof(int), stream);
    hipMemsetAsync(gsum, 0, (size_t)GG * 128 * sizeof(float), stream);

    bounds_kernel<<<(NN + 255) / 256, 256, 0, stream>>>(batch, se);

    // ---- CSR build + slot-order edge materialization (shared by both layers) ----
    deg_kernel<<<(EE + 255) / 256, 256, 0, stream>>>(ei, cursor);
    scan1_kernel<<<NB1, 256, 0, stream>>>(cursor, rowptr, partials);
    scan2_kernel<<<1, 256, 0, stream>>>(partials);
    scan3_kernel<<<NB1, 256, 0, stream>>>(rowptr, partials);
    hipMemsetAsync(cursor, 0, (size_t)NN * sizeof(int), stream);
    scatter_kernel<<<(EE + 255) / 256, 256, 0, stream>>>(ei, rowptr, cursor, eidx, esrc);
    permute_kernel<<<(EE + 15) / 16, 256, 0, stream>>>(ea, eidx, eaperm);

    // ---- layer 1 ----
    agg_pass<<<(NN + 3) / 4, 256, 0, stream>>>(x, eaperm, esrc, e1w, e1b, rowptr, cursor, agg);
    node1_fused<<<(NN + 63) / 64, 256, 0, stream>>>(agg, n1w1, n1b1, n1w2, n1b2, h1, NN);

    // ---- layer 2 (fused gather + GEMM + pool; no agg/H2 round-trip) ----
    agg_gemm_pool<<<(NN + 63) / 64, 256, 0, stream>>>(h1, eaperm, esrc, e2w, e2b,
                                                      rowptr, cursor, n2w1, n2b1,
                                                      batch, gsum, NN);

    // ---- head ----
    head_kernel<<<GG, 128, 0, stream>>>(gsum, se, usr, n2w2, n2b2,
                                        h1w, h1b, h2w, h2b, h3w, h3b, h4w, h4b, h5w, h5b,
                                        (float*)d_out);
}

// Round 14
// 532.074 us; speedup vs baseline: 1.0489x; 1.0489x over previous
//
#include <hip/hip_runtime.h>

#define NN 200000
#define EE 400000
#define GG 4096

// ws layout (float offsets)
#define AGG_OFF 0
#define H1_OFF  (NN * 64)                  // 12,800,000
#define SE_OFF  (H1_OFF + NN * 64)         // 25,600,000 (2*GG ints)
#define GSUM_OFF (SE_OFF + 2 * GG)         // per-graph H2 sums (GG*128 floats)
#define CSR_OFF (GSUM_OFF + GG * 128)      // CSR + permuted edges; never clobbered

#define NB1 ((NN + 1023) / 1024)           // 196 scan blocks

// ---------------- segment boundaries from sorted batch ----------------
__global__ void bounds_kernel(const int* __restrict__ batch, int* __restrict__ se) {
    int n = blockIdx.x * blockDim.x + threadIdx.x;
    if (n >= NN) return;
    int b = batch[n];
    if (n == 0 || batch[n - 1] != b) se[b] = n;                 // start
    if (n == NN - 1 || batch[n + 1] != b) se[GG + b] = n + 1;   // end
}

// ---------------- CSR build ----------------
__global__ void deg_kernel(const int* __restrict__ ei, int* __restrict__ cursor) {
    int e = blockIdx.x * blockDim.x + threadIdx.x;
    if (e >= EE) return;
    atomicAdd(cursor + ei[EE + e], 1);
}

__global__ __launch_bounds__(256) void scan1_kernel(const int* __restrict__ deg,
                                                    int* __restrict__ rowptr,
                                                    int* __restrict__ partials) {
    __shared__ int sdata[256];
    int t = threadIdx.x;
    int base = blockIdx.x * 1024 + t * 4;
    int v[4]; int s = 0;
#pragma unroll
    for (int j = 0; j < 4; j++) {
        v[j] = (base + j < NN) ? deg[base + j] : 0;
        s += v[j];
    }
    sdata[t] = s;
    __syncthreads();
#pragma unroll
    for (int off = 1; off < 256; off <<= 1) {
        int x = (t >= off) ? sdata[t - off] : 0;
        __syncthreads();
        sdata[t] += x;
        __syncthreads();
    }
    int run = sdata[t] - s;
#pragma unroll
    for (int j = 0; j < 4; j++) {
        if (base + j < NN) rowptr[base + j] = run;
        run += v[j];
    }
    if (t == 255) partials[blockIdx.x] = sdata[255];
}

__global__ __launch_bounds__(256) void scan2_kernel(int* __restrict__ partials) {
    __shared__ int sdata[256];
    int t = threadIdx.x;
    int p = (t < NB1) ? partials[t] : 0;
    sdata[t] = p;
    __syncthreads();
#pragma unroll
    for (int off = 1; off < 256; off <<= 1) {
        int x = (t >= off) ? sdata[t - off] : 0;
        __syncthreads();
        sdata[t] += x;
        __syncthreads();
    }
    if (t < NB1) partials[t] = sdata[t] - p;
}

__global__ __launch_bounds__(256) void scan3_kernel(int* __restrict__ rowptr,
                                                    const int* __restrict__ partials) {
    int t = threadIdx.x;
    int add = partials[blockIdx.x];
    int base = blockIdx.x * 1024 + t * 4;
#pragma unroll
    for (int j = 0; j < 4; j++)
        if (base + j < NN) rowptr[base + j] += add;
}

__global__ void scatter_kernel(const int* __restrict__ ei,
                               const int* __restrict__ rowptr,
                               int* __restrict__ cursor,
                               int* __restrict__ eidx,
                               int* __restrict__ esrc) {
    int e = blockIdx.x * blockDim.x + threadIdx.x;
    if (e >= EE) return;
    int d = ei[EE + e];
    int pos = rowptr[d] + atomicAdd(cursor + d, 1);
    eidx[pos] = e;
    esrc[pos] = ei[e];
}

// permute edge attrs into slot order: eaperm[p] = ea[eidx[p]]
__global__ __launch_bounds__(256) void permute_kernel(const float* __restrict__ ea,
                                                      const int* __restrict__ eidx,
                                                      float* __restrict__ eaperm) {
    int p4 = blockIdx.x * 16 + (threadIdx.x >> 4);
    if (p4 >= EE) return;
    int elem = threadIdx.x & 15;
    int e = eidx[p4];
    eaperm[(size_t)p4 * 16 + elem] = ea[(size_t)e * 16 + elem];
}

// ---------------- gather aggregation (no atomics; ew/eb staged in LDS) -------
// Per-wave VMEM preamble cut from 17 loads to ~3: Wr comes from LDS
// (ds_read_b32, 2-way bank alias = free), staged once per block.
__global__ __launch_bounds__(256) void agg_pass(const float* __restrict__ xin,
                                                const float* __restrict__ eaperm,
                                                const int* __restrict__ esrc,
                                                const float* __restrict__ ew,
                                                const float* __restrict__ eb,
                                                const int* __restrict__ rowptr,
                                                const int* __restrict__ cnt,
                                                float* __restrict__ agg) {
    __shared__ float ews[16 * 64];
    __shared__ float ebs[64];

    {
        const float4* src = (const float4*)ew;
        float4* dst = (float4*)ews;
        if (threadIdx.x < 256) dst[threadIdx.x] = src[threadIdx.x];   // 1024 floats
        if (threadIdx.x < 16) ((float4*)ebs)[threadIdx.x] = ((const float4*)eb)[threadIdx.x];
    }
    __syncthreads();   // single barrier; partial-tail threads pass through it

    const int lane = threadIdx.x & 63;
    int n = blockIdx.x * 4 + (threadIdx.x >> 6);
    if (n >= NN) return;

    float Wr[16];
#pragma unroll
    for (int k = 0; k < 16; k++) Wr[k] = ews[k * 64 + lane];
    const float br = ebs[lane];

    int s   = __builtin_amdgcn_readfirstlane(rowptr[n]);
    int deg = __builtin_amdgcn_readfirstlane(cnt[n]);

    float sum = xin[(size_t)n * 64 + lane];

    for (int i = 0; i < deg; i += 2) {
        const bool two = (i + 1 < deg);
        const int p0 = s + i, p1 = s + i + 1;
        int s0 = esrc[p0];
        int s1 = two ? esrc[p1] : s0;
        const float4* q0 = (const float4*)(eaperm + (size_t)p0 * 16);
        const float4* q1 = (const float4*)(eaperm + (size_t)p1 * 16);
        float4 A0 = q0[0], A1 = q0[1], A2 = q0[2], A3 = q0[3];
        float4 B0, B1, B2, B3;
        if (two) { B0 = q1[0]; B1 = q1[1]; B2 = q1[2]; B3 = q1[3]; }
        float xv0 = xin[(size_t)s0 * 64 + lane];
        float xv1 = two ? xin[(size_t)s1 * 64 + lane] : 0.0f;

        float acc0 = br;
        acc0 += A0.x * Wr[0];  acc0 += A0.y * Wr[1];
        acc0 += A0.z * Wr[2];  acc0 += A0.w * Wr[3];
        acc0 += A1.x * Wr[4];  acc0 += A1.y * Wr[5];
        acc0 += A1.z * Wr[6];  acc0 += A1.w * Wr[7];
        acc0 += A2.x * Wr[8];  acc0 += A2.y * Wr[9];
        acc0 += A2.z * Wr[10]; acc0 += A2.w * Wr[11];
        acc0 += A3.x * Wr[12]; acc0 += A3.y * Wr[13];
        acc0 += A3.z * Wr[14]; acc0 += A3.w * Wr[15];
        sum += fmaxf(acc0 + xv0, 0.0f);
        if (two) {
            float acc1 = br;
            acc1 += B0.x * Wr[0];  acc1 += B0.y * Wr[1];
            acc1 += B0.z * Wr[2];  acc1 += B0.w * Wr[3];
            acc1 += B1.x * Wr[4];  acc1 += B1.y * Wr[5];
            acc1 += B1.z * Wr[6];  acc1 += B1.w * Wr[7];
            acc1 += B2.x * Wr[8];  acc1 += B2.y * Wr[9];
            acc1 += B2.z * Wr[10]; acc1 += B2.w * Wr[11];
            acc1 += B3.x * Wr[12]; acc1 += B3.y * Wr[13];
            acc1 += B3.z * Wr[14]; acc1 += B3.w * Wr[15];
            sum += fmaxf(acc1 + xv1, 0.0f);
        }
    }
    agg[(size_t)n * 64 + lane] = sum;
}

// ---------------- fused node-1 MLP: Y = relu( relu(X@W1+b1) @ W2 + b2 ) ------
__global__ __launch_bounds__(256) void node1_fused(const float* __restrict__ X,
                                                   const float* __restrict__ W1,
                                                   const float* __restrict__ B1,
                                                   const float* __restrict__ W2,
                                                   const float* __restrict__ B2,
                                                   float* __restrict__ Y,
                                                   int rows) {
    __shared__ float W1s[64 * 64];
    __shared__ float W2s[64 * 64];
    __shared__ float Hs[64 * 68];

    {
        const float4* s1 = (const float4*)W1;
        const float4* s2 = (const float4*)W2;
        float4* d1 = (float4*)W1s;
        float4* d2 = (float4*)W2s;
        for (int i = threadIdx.x; i < 1024; i += 256) { d1[i] = s1[i]; d2[i] = s2[i]; }
    }

    const int cg = threadIdx.x % 8;
    const int rg = threadIdx.x / 8;
    const int c0a = cg * 4, c0b = 32 + cg * 4;
    const int rbase = blockIdx.x * 64 + rg * 2;

    const float* xptr[2];
#pragma unroll
    for (int r = 0; r < 2; r++) {
        int rr = rbase + r;
        int ri = (rr < rows) ? rr : (rows - 1);
        xptr[r] = X + (size_t)ri * 64;
    }

    float acc[2][8];
    {
        const float4 v0 = *(const float4*)(B1 + c0a);
        const float4 v1 = *(const float4*)(B1 + c0b);
#pragma unroll
        for (int r = 0; r < 2; r++) {
            acc[r][0] = v0.x; acc[r][1] = v0.y; acc[r][2] = v0.z; acc[r][3] = v0.w;
            acc[r][4] = v1.x; acc[r][5] = v1.y; acc[r][6] = v1.z; acc[r][7] = v1.w;
        }
    }

    float4 a_cur[2], a_nxt[2];
#pragma unroll
    for (int r = 0; r < 2; r++) a_cur[r] = *(const float4*)(xptr[r]);

    __syncthreads();

#pragma unroll 2
    for (int k4 = 0; k4 < 64; k4 += 4) {
        if (k4 + 4 < 64) {
#pragma unroll
            for (int r = 0; r < 2; r++) a_nxt[r] = *(const float4*)(xptr[r] + k4 + 4);
        }
#pragma unroll
        for (int kk = 0; kk < 4; kk++) {
            const float4 w0 = *(const float4*)(W1s + (k4 + kk) * 64 + c0a);
            const float4 w1 = *(const float4*)(W1s + (k4 + kk) * 64 + c0b);
#pragma unroll
            for (int r = 0; r < 2; r++) {
                float av = (kk == 0) ? a_cur[r].x : (kk == 1) ? a_cur[r].y
                         : (kk == 2) ? a_cur[r].z : a_cur[r].w;
                acc[r][0] += av * w0.x; acc[r][1] += av * w0.y;
                acc[r][2] += av * w0.z; acc[r][3] += av * w0.w;
                acc[r][4] += av * w1.x; acc[r][5] += av * w1.y;
                acc[r][6] += av * w1.z; acc[r][7] += av * w1.w;
            }
        }
#pragma unroll
        for (int r = 0; r < 2; r++) a_cur[r] = a_nxt[r];
    }

#pragma unroll
    for (int r = 0; r < 2; r++) {
        const int lrow = rg * 2 + r;
        float4 v0, v1;
        v0.x = fmaxf(acc[r][0], 0.0f); v0.y = fmaxf(acc[r][1], 0.0f);
        v0.z = fmaxf(acc[r][2], 0.0f); v0.w = fmaxf(acc[r][3], 0.0f);
        v1.x = fmaxf(acc[r][4], 0.0f); v1.y = fmaxf(acc[r][5], 0.0f);
        v1.z = fmaxf(acc[r][6], 0.0f); v1.w = fmaxf(acc[r][7], 0.0f);
        *(float4*)(Hs + lrow * 68 + c0a) = v0;
        *(float4*)(Hs + lrow * 68 + c0b) = v1;
    }

    {
        const float4 v0 = *(const float4*)(B2 + c0a);
        const float4 v1 = *(const float4*)(B2 + c0b);
#pragma unroll
        for (int r = 0; r < 2; r++) {
            acc[r][0] = v0.x; acc[r][1] = v0.y; acc[r][2] = v0.z; acc[r][3] = v0.w;
            acc[r][4] = v1.x; acc[r][5] = v1.y; acc[r][6] = v1.z; acc[r][7] = v1.w;
        }
    }
    __syncthreads();

#pragma unroll 2
    for (int k4 = 0; k4 < 64; k4 += 4) {
        float4 a[2];
#pragma unroll
        for (int r = 0; r < 2; r++) a[r] = *(const float4*)(Hs + (rg * 2 + r) * 68 + k4);
#pragma unroll
        for (int kk = 0; kk < 4; kk++) {
            const float4 w0 = *(const float4*)(W2s + (k4 + kk) * 64 + c0a);
            const float4 w1 = *(const float4*)(W2s + (k4 + kk) * 64 + c0b);
#pragma unroll
            for (int r = 0; r < 2; r++) {
                float av = (kk == 0) ? a[r].x : (kk == 1) ? a[r].y
                         : (kk == 2) ? a[r].z : a[r].w;
                acc[r][0] += av * w0.x; acc[r][1] += av * w0.y;
                acc[r][2] += av * w0.z; acc[r][3] += av * w0.w;
                acc[r][4] += av * w1.x; acc[r][5] += av * w1.y;
                acc[r][6] += av * w1.z; acc[r][7] += av * w1.w;
            }
        }
    }

#pragma unroll
    for (int r = 0; r < 2; r++) {
        int rr = rbase + r;
        if (rr < rows) {
            float4 v0, v1;
            v0.x = fmaxf(acc[r][0], 0.0f); v0.y = fmaxf(acc[r][1], 0.0f);
            v0.z = fmaxf(acc[r][2], 0.0f); v0.w = fmaxf(acc[r][3], 0.0f);
            v1.x = fmaxf(acc[r][4], 0.0f); v1.y = fmaxf(acc[r][5], 0.0f);
            v1.z = fmaxf(acc[r][6], 0.0f); v1.w = fmaxf(acc[r][7], 0.0f);
            *(float4*)(Y + (size_t)rr * 64 + c0a) = v0;
            *(float4*)(Y + (size_t)rr * 64 + c0b) = v1;
        }
    }
}

// ---------------- n2a GEMM fused with graph pooling (R11 36.9 KB variant) ----
__global__ __launch_bounds__(256) void gemm_pool(const float* __restrict__ X,
                                                 const float* __restrict__ W,
                                                 const float* __restrict__ Bv,
                                                 const int* __restrict__ batch,
                                                 float* __restrict__ gsum,
                                                 int rows) {
    constexpr int K = 64, C = 128;
    constexpr int CPT = 8, RPT = 4, COLG = 16;
    constexpr int BR = 64;

    __shared__ float Bs[K * C];        // 32 KB
    __shared__ float pool[8 * C];      // 4 KB

    const int cg = threadIdx.x % COLG;
    const int rg = threadIdx.x / COLG;
    const int c0a = cg * 4;
    const int c0b = 64 + cg * 4;
    const int rbase = blockIdx.x * BR + rg * RPT;

    {
        const float4* wsrc = (const float4*)W;
        float4* wdst = (float4*)Bs;
        for (int i = threadIdx.x; i < K * C / 4; i += 256) wdst[i] = wsrc[i];
    }
    for (int i = threadIdx.x; i < 8 * C; i += 256) pool[i] = 0.0f;

    int r0 = blockIdx.x * BR; if (r0 > rows - 1) r0 = rows - 1;
    int r1 = blockIdx.x * BR + BR - 1; if (r1 > rows - 1) r1 = rows - 1;
    const int gfirst = batch[r0];
    const int glast  = batch[r1];
    const int span = glast - gfirst + 1;
    const bool useLds = (span <= 8);

    const float* xptr[RPT];
    int gid[RPT];
#pragma unroll
    for (int r = 0; r < RPT; r++) {
        int rr = rbase + r;
        int ri = (rr < rows) ? rr : (rows - 1);
        xptr[r] = X + (size_t)ri * K;
        gid[r] = batch[ri];
    }

    float acc[RPT][CPT];
    {
        const float4 v0 = *(const float4*)(Bv + c0a);
        const float4 v1 = *(const float4*)(Bv + c0b);
#pragma unroll
        for (int r = 0; r < RPT; r++) {
            acc[r][0] = v0.x; acc[r][1] = v0.y; acc[r][2] = v0.z; acc[r][3] = v0.w;
            acc[r][4] = v1.x; acc[r][5] = v1.y; acc[r][6] = v1.z; acc[r][7] = v1.w;
        }
    }

    float4 a_cur[RPT], a_nxt[RPT];
#pragma unroll
    for (int r = 0; r < RPT; r++) a_cur[r] = *(const float4*)(xptr[r]);

    __syncthreads();   // Bs staged, pool zeroed

#pragma unroll 2
    for (int k4 = 0; k4 < K; k4 += 4) {
        if (k4 + 4 < K) {
#pragma unroll
            for (int r = 0; r < RPT; r++) a_nxt[r] = *(const float4*)(xptr[r] + k4 + 4);
        }
#pragma unroll
        for (int kk = 0; kk < 4; kk++) {
            const float4 w0 = *(const float4*)(Bs + (k4 + kk) * C + c0a);
            const float4 w1 = *(const float4*)(Bs + (k4 + kk) * C + c0b);
#pragma unroll
            for (int r = 0; r < RPT; r++) {
                float av = (kk == 0) ? a_cur[r].x : (kk == 1) ? a_cur[r].y
                         : (kk == 2) ? a_cur[r].z : a_cur[r].w;
                acc[r][0] += av * w0.x; acc[r][1] += av * w0.y;
                acc[r][2] += av * w0.z; acc[r][3] += av * w0.w;
                acc[r][4] += av * w1.x; acc[r][5] += av * w1.y;
                acc[r][6] += av * w1.z; acc[r][7] += av * w1.w;
            }
        }
#pragma unroll
        for (int r = 0; r < RPT; r++) a_cur[r] = a_nxt[r];
    }

    // ---- register run-reduction over this thread's 4 consecutive rows ----
    float part[CPT];
    int curg = -1;
#pragma unroll 1
    for (int r = 0; r < RPT; r++) {
        int rr = rbase + r;
        if (rr >= rows) break;
        int g = gid[r];
        if (g != curg) {
            if (curg >= 0) {
                float* p = useLds ? (pool + (curg - gfirst) * C)
                                  : (gsum + (size_t)curg * C);
#pragma unroll
                for (int j = 0; j < 4; j++) atomicAdd(p + c0a + j, part[j]);
#pragma unroll
                for (int j = 0; j < 4; j++) atomicAdd(p + c0b + j, part[4 + j]);
            }
            curg = g;
#pragma unroll
            for (int j = 0; j < CPT; j++) part[j] = 0.0f;
        }
#pragma unroll
        for (int j = 0; j < CPT; j++) part[j] += fmaxf(acc[r][j], 0.0f);
    }
    if (curg >= 0) {
        float* p = useLds ? (pool + (curg - gfirst) * C)
                          : (gsum + (size_t)curg * C);
#pragma unroll
        for (int j = 0; j < 4; j++) atomicAdd(p + c0a + j, part[j]);
#pragma unroll
        for (int j = 0; j < 4; j++) atomicAdd(p + c0b + j, part[4 + j]);
    }

    if (useLds) {
        __syncthreads();
        for (int i = threadIdx.x; i < span * C; i += 256) {
            float v = pool[i];
            if (v != 0.0f)
                atomicAdd(gsum + (size_t)(gfirst + (i >> 7)) * C + (i & 127), v);
        }
    }
}

// ---------------- head: m = gsum/cnt, emb = m@W2+b2 (commuted), 5-layer MLP ----
__global__ __launch_bounds__(128) void head_kernel(const float* __restrict__ gsum,
                                                   const int* __restrict__ se,
                                                   const float* __restrict__ usr,
                                                   const float* __restrict__ w2, const float* __restrict__ b2,
                                                   const float* __restrict__ h1w, const float* __restrict__ h1b,
                                                   const float* __restrict__ h2w, const float* __restrict__ h2b,
                                                   const float* __restrict__ h3w, const float* __restrict__ h3b,
                                                   const float* __restrict__ h4w, const float* __restrict__ h4b,
                                                   const float* __restrict__ h5w, const float* __restrict__ h5b,
                                                   float* __restrict__ out) {
    int g = blockIdx.x;
    int c = threadIdx.x;
    __shared__ float m[128];
    __shared__ float z0[140];
    __shared__ float z1[128];
    __shared__ float z2[64];
    __shared__ float z3[32];
    __shared__ float z4[16];

    int s = se[g], e = se[GG + g];
    float cnt = fmaxf((float)(e - s), 1.0f);
    m[c] = gsum[(size_t)g * 128 + c] / cnt;
    __syncthreads();

    {
        float acc = b2[c];
        for (int k = 0; k < 128; k++) acc += m[k] * w2[k * 128 + c];
        z0[c] = (e > s) ? acc : 0.0f;
    }
    if (c < 12) z0[128 + c] = usr[g * 12 + c];
    __syncthreads();

    {
        float acc = h1b[c];
        for (int k = 0; k < 140; k++) acc += z0[k] * h1w[k * 128 + c];
        z1[c] = fmaxf(acc, 0.0f);
    }
    __syncthreads();
    if (c < 64) {
        float acc = h2b[c];
        for (int k = 0; k < 128; k++) acc += z1[k] * h2w[k * 64 + c];
        z2[c] = fmaxf(acc, 0.0f);
    }
    __syncthreads();
    if (c < 32) {
        float acc = h3b[c];
        for (int k = 0; k < 64; k++) acc += z2[k] * h3w[k * 32 + c];
        z3[c] = fmaxf(acc, 0.0f);
    }
    __syncthreads();
    if (c < 16) {
        float acc = h4b[c];
        for (int k = 0; k < 32; k++) acc += z3[k] * h4w[k * 16 + c];
        z4[c] = fmaxf(acc, 0.0f);
    }
    __syncthreads();
    if (c == 0) {
        float acc = h5b[0];
        for (int k = 0; k < 16; k++) acc += z4[k] * h5w[k];
        out[g] = acc;
    }
}

extern "C" void kernel_launch(void* const* d_in, const int* in_sizes, int n_in,
                              void* d_out, int out_size, void* d_ws, size_t ws_size,
                              hipStream_t stream) {
    const float* x    = (const float*)d_in[0];
    const int*   ei   = (const int*)d_in[1];
    const float* ea   = (const float*)d_in[2];
    const int*   batch= (const int*)d_in[3];
    const float* usr  = (const float*)d_in[4];
    const float* e1w  = (const float*)d_in[5],  *e1b  = (const float*)d_in[6];
    const float* n1w1 = (const float*)d_in[7],  *n1b1 = (const float*)d_in[8];
    const float* n1w2 = (const float*)d_in[9],  *n1b2 = (const float*)d_in[10];
    const float* e2w  = (const float*)d_in[11], *e2b  = (const float*)d_in[12];
    const float* n2w1 = (const float*)d_in[13], *n2b1 = (const float*)d_in[14];
    const float* n2w2 = (const float*)d_in[15], *n2b2 = (const float*)d_in[16];
    const float* h1w  = (const float*)d_in[17], *h1b  = (const float*)d_in[18];
    const float* h2w  = (const float*)d_in[19], *h2b  = (const float*)d_in[20];
    const float* h3w  = (const float*)d_in[21], *h3b  = (const float*)d_in[22];
    const float* h4w  = (const float*)d_in[23], *h4b  = (const float*)d_in[24];
    const float* h5w  = (const float*)d_in[25], *h5b  = (const float*)d_in[26];

    float* w    = (float*)d_ws;
    float* agg  = w + AGG_OFF;
    float* h1   = w + H1_OFF;
    int*   se   = (int*)(w + SE_OFF);
    float* gsum = w + GSUM_OFF;

    int*   rowptr   = (int*)(w + CSR_OFF);
    int*   cursor   = rowptr + NN;
    int*   eidx     = cursor + NN;
    int*   esrc     = eidx + EE;
    int*   partials = esrc + EE;
    float* eaperm   = (float*)(partials + 256);

    hipMemsetAsync(se, 0, (size_t)GG * 2 * sizeof(int), stream);
    hipMemsetAsync(cursor, 0, (size_t)NN * sizeof(int), stream);
    hipMemsetAsync(gsum, 0, (size_t)GG * 128 * sizeof(float), stream);

    bounds_kernel<<<(NN + 255) / 256, 256, 0, stream>>>(batch, se);

    // ---- CSR build + slot-order edge materialization (shared by both layers) ----
    deg_kernel<<<(EE + 255) / 256, 256, 0, stream>>>(ei, cursor);
    scan1_kernel<<<NB1, 256, 0, stream>>>(cursor, rowptr, partials);
    scan2_kernel<<<1, 256, 0, stream>>>(partials);
    scan3_kernel<<<NB1, 256, 0, stream>>>(rowptr, partials);
    hipMemsetAsync(cursor, 0, (size_t)NN * sizeof(int), stream);
    scatter_kernel<<<(EE + 255) / 256, 256, 0, stream>>>(ei, rowptr, cursor, eidx, esrc);
    permute_kernel<<<(EE + 15) / 16, 256, 0, stream>>>(ea, eidx, eaperm);

    // ---- layer 1 ----
    agg_pass<<<(NN + 3) / 4, 256, 0, stream>>>(x, eaperm, esrc, e1w, e1b, rowptr, cursor, agg);
    node1_fused<<<(NN + 63) / 64, 256, 0, stream>>>(agg, n1w1, n1b1, n1w2, n1b2, h1, NN);

    // ---- layer 2 ----
    agg_pass<<<(NN + 3) / 4, 256, 0, stream>>>(h1, eaperm, esrc, e2w, e2b, rowptr, cursor, agg);
    gemm_pool<<<(NN + 63) / 64, 256, 0, stream>>>(agg, n2w1, n2b1, batch, gsum, NN);

    // ---- head ----
    head_kernel<<<GG, 128, 0, stream>>>(gsum, se, usr, n2w2, n2b2,
                                        h1w, h1b, h2w, h2b, h3w, h3b, h4w, h4b, h5w, h5b,
                                        (float*)d_out);
}

// Round 15
// 513.191 us; speedup vs baseline: 1.0875x; 1.0368x over previous
//
#include <hip/hip_runtime.h>

#define NN 200000
#define EE 400000
#define GG 4096

// ws layout (float offsets)
#define AGG_OFF 0
#define H1_OFF  (NN * 64)                  // 12,800,000
#define SE_OFF  (H1_OFF + NN * 64)         // 25,600,000 (2*GG ints)
#define GSUM_OFF (SE_OFF + 2 * GG)         // per-graph H2 sums (GG*128 floats)
#define CSR_OFF (GSUM_OFF + GG * 128)      // CSR + permuted edges; never clobbered

#define NB1 ((NN + 1023) / 1024)           // 196 scan blocks

// ---------------- segment boundaries from sorted batch ----------------
__global__ void bounds_kernel(const int* __restrict__ batch, int* __restrict__ se) {
    int n = blockIdx.x * blockDim.x + threadIdx.x;
    if (n >= NN) return;
    int b = batch[n];
    if (n == 0 || batch[n - 1] != b) se[b] = n;                 // start
    if (n == NN - 1 || batch[n + 1] != b) se[GG + b] = n + 1;   // end
}

// ---------------- CSR build ----------------
__global__ void deg_kernel(const int* __restrict__ ei, int* __restrict__ cursor) {
    int e = blockIdx.x * blockDim.x + threadIdx.x;
    if (e >= EE) return;
    atomicAdd(cursor + ei[EE + e], 1);
}

__global__ __launch_bounds__(256) void scan1_kernel(const int* __restrict__ deg,
                                                    int* __restrict__ rowptr,
                                                    int* __restrict__ partials) {
    __shared__ int sdata[256];
    int t = threadIdx.x;
    int base = blockIdx.x * 1024 + t * 4;
    int v[4]; int s = 0;
#pragma unroll
    for (int j = 0; j < 4; j++) {
        v[j] = (base + j < NN) ? deg[base + j] : 0;
        s += v[j];
    }
    sdata[t] = s;
    __syncthreads();
#pragma unroll
    for (int off = 1; off < 256; off <<= 1) {
        int x = (t >= off) ? sdata[t - off] : 0;
        __syncthreads();
        sdata[t] += x;
        __syncthreads();
    }
    int run = sdata[t] - s;
#pragma unroll
    for (int j = 0; j < 4; j++) {
        if (base + j < NN) rowptr[base + j] = run;
        run += v[j];
    }
    if (t == 255) partials[blockIdx.x] = sdata[255];
}

__global__ __launch_bounds__(256) void scan2_kernel(int* __restrict__ partials) {
    __shared__ int sdata[256];
    int t = threadIdx.x;
    int p = (t < NB1) ? partials[t] : 0;
    sdata[t] = p;
    __syncthreads();
#pragma unroll
    for (int off = 1; off < 256; off <<= 1) {
        int x = (t >= off) ? sdata[t - off] : 0;
        __syncthreads();
        sdata[t] += x;
        __syncthreads();
    }
    if (t < NB1) partials[t] = sdata[t] - p;
}

__global__ __launch_bounds__(256) void scan3_kernel(int* __restrict__ rowptr,
                                                    const int* __restrict__ partials) {
    int t = threadIdx.x;
    int add = partials[blockIdx.x];
    int base = blockIdx.x * 1024 + t * 4;
#pragma unroll
    for (int j = 0; j < 4; j++)
        if (base + j < NN) rowptr[base + j] += add;
}

__global__ void scatter_kernel(const int* __restrict__ ei,
                               const int* __restrict__ rowptr,
                               int* __restrict__ cursor,
                               int* __restrict__ eidx,
                               int* __restrict__ esrc) {
    int e = blockIdx.x * blockDim.x + threadIdx.x;
    if (e >= EE) return;
    int d = ei[EE + e];
    int pos = rowptr[d] + atomicAdd(cursor + d, 1);
    eidx[pos] = e;
    esrc[pos] = ei[e];
}

// permute edge attrs into slot order: eaperm[p] = ea[eidx[p]]
__global__ __launch_bounds__(256) void permute_kernel(const float* __restrict__ ea,
                                                      const int* __restrict__ eidx,
                                                      float* __restrict__ eaperm) {
    int p4 = blockIdx.x * 16 + (threadIdx.x >> 4);
    if (p4 >= EE) return;
    int elem = threadIdx.x & 15;
    int e = eidx[p4];
    eaperm[(size_t)p4 * 16 + elem] = ea[(size_t)e * 16 + elem];
}

// ---------------- gather aggregation (no atomics, short chains) ----------------
// agg[n] = xin[n] + sum_{slots p of n} relu(eaperm[p]@W + b + xin[esrc[p]])
// wave per node (maximal independent waves — measured optimum), 2-edge unroll.
__global__ __launch_bounds__(256) void agg_pass(const float* __restrict__ xin,
                                                const float* __restrict__ eaperm,
                                                const int* __restrict__ esrc,
                                                const float* __restrict__ ew,
                                                const float* __restrict__ eb,
                                                const int* __restrict__ rowptr,
                                                const int* __restrict__ cnt,
                                                float* __restrict__ agg) {
    const int lane = threadIdx.x & 63;
    int n = blockIdx.x * 4 + (threadIdx.x >> 6);
    if (n >= NN) return;

    float Wr[16];
#pragma unroll
    for (int k = 0; k < 16; k++) Wr[k] = ew[k * 64 + lane];
    const float br = eb[lane];

    int s   = __builtin_amdgcn_readfirstlane(rowptr[n]);
    int deg = __builtin_amdgcn_readfirstlane(cnt[n]);

    float sum = xin[(size_t)n * 64 + lane];

    for (int i = 0; i < deg; i += 2) {
        const bool two = (i + 1 < deg);
        const int p0 = s + i, p1 = s + i + 1;
        // uniform vector loads; values feed address math directly (no s-roundtrip)
        int s0 = esrc[p0];
        int s1 = two ? esrc[p1] : s0;
        const float4* q0 = (const float4*)(eaperm + (size_t)p0 * 16);
        const float4* q1 = (const float4*)(eaperm + (size_t)p1 * 16);
        float4 A0 = q0[0], A1 = q0[1], A2 = q0[2], A3 = q0[3];
        float4 B0, B1, B2, B3;
        if (two) { B0 = q1[0]; B1 = q1[1]; B2 = q1[2]; B3 = q1[3]; }
        float xv0 = xin[(size_t)s0 * 64 + lane];
        float xv1 = two ? xin[(size_t)s1 * 64 + lane] : 0.0f;

        float acc0 = br;
        acc0 += A0.x * Wr[0];  acc0 += A0.y * Wr[1];
        acc0 += A0.z * Wr[2];  acc0 += A0.w * Wr[3];
        acc0 += A1.x * Wr[4];  acc0 += A1.y * Wr[5];
        acc0 += A1.z * Wr[6];  acc0 += A1.w * Wr[7];
        acc0 += A2.x * Wr[8];  acc0 += A2.y * Wr[9];
        acc0 += A2.z * Wr[10]; acc0 += A2.w * Wr[11];
        acc0 += A3.x * Wr[12]; acc0 += A3.y * Wr[13];
        acc0 += A3.z * Wr[14]; acc0 += A3.w * Wr[15];
        sum += fmaxf(acc0 + xv0, 0.0f);
        if (two) {
            float acc1 = br;
            acc1 += B0.x * Wr[0];  acc1 += B0.y * Wr[1];
            acc1 += B0.z * Wr[2];  acc1 += B0.w * Wr[3];
            acc1 += B1.x * Wr[4];  acc1 += B1.y * Wr[5];
            acc1 += B1.z * Wr[6];  acc1 += B1.w * Wr[7];
            acc1 += B2.x * Wr[8];  acc1 += B2.y * Wr[9];
            acc1 += B2.z * Wr[10]; acc1 += B2.w * Wr[11];
            acc1 += B3.x * Wr[12]; acc1 += B3.y * Wr[13];
            acc1 += B3.z * Wr[14]; acc1 += B3.w * Wr[15];
            sum += fmaxf(acc1 + xv1, 0.0f);
        }
    }
    agg[(size_t)n * 64 + lane] = sum;
}

// ---------------- fused node-1 MLP: Y = relu( relu(X@W1+b1) @ W2 + b2 ) ------
__global__ __launch_bounds__(256) void node1_fused(const float* __restrict__ X,
                                                   const float* __restrict__ W1,
                                                   const float* __restrict__ B1,
                                                   const float* __restrict__ W2,
                                                   const float* __restrict__ B2,
                                                   float* __restrict__ Y,
                                                   int rows) {
    __shared__ float W1s[64 * 64];
    __shared__ float W2s[64 * 64];
    __shared__ float Hs[64 * 68];

    {
        const float4* s1 = (const float4*)W1;
        const float4* s2 = (const float4*)W2;
        float4* d1 = (float4*)W1s;
        float4* d2 = (float4*)W2s;
        for (int i = threadIdx.x; i < 1024; i += 256) { d1[i] = s1[i]; d2[i] = s2[i]; }
    }

    const int cg = threadIdx.x % 8;
    const int rg = threadIdx.x / 8;
    const int c0a = cg * 4, c0b = 32 + cg * 4;
    const int rbase = blockIdx.x * 64 + rg * 2;

    const float* xptr[2];
#pragma unroll
    for (int r = 0; r < 2; r++) {
        int rr = rbase + r;
        int ri = (rr < rows) ? rr : (rows - 1);
        xptr[r] = X + (size_t)ri * 64;
    }

    float acc[2][8];
    {
        const float4 v0 = *(const float4*)(B1 + c0a);
        const float4 v1 = *(const float4*)(B1 + c0b);
#pragma unroll
        for (int r = 0; r < 2; r++) {
            acc[r][0] = v0.x; acc[r][1] = v0.y; acc[r][2] = v0.z; acc[r][3] = v0.w;
            acc[r][4] = v1.x; acc[r][5] = v1.y; acc[r][6] = v1.z; acc[r][7] = v1.w;
        }
    }

    float4 a_cur[2], a_nxt[2];
#pragma unroll
    for (int r = 0; r < 2; r++) a_cur[r] = *(const float4*)(xptr[r]);

    __syncthreads();

#pragma unroll 2
    for (int k4 = 0; k4 < 64; k4 += 4) {
        if (k4 + 4 < 64) {
#pragma unroll
            for (int r = 0; r < 2; r++) a_nxt[r] = *(const float4*)(xptr[r] + k4 + 4);
        }
#pragma unroll
        for (int kk = 0; kk < 4; kk++) {
            const float4 w0 = *(const float4*)(W1s + (k4 + kk) * 64 + c0a);
            const float4 w1 = *(const float4*)(W1s + (k4 + kk) * 64 + c0b);
#pragma unroll
            for (int r = 0; r < 2; r++) {
                float av = (kk == 0) ? a_cur[r].x : (kk == 1) ? a_cur[r].y
                         : (kk == 2) ? a_cur[r].z : a_cur[r].w;
                acc[r][0] += av * w0.x; acc[r][1] += av * w0.y;
                acc[r][2] += av * w0.z; acc[r][3] += av * w0.w;
                acc[r][4] += av * w1.x; acc[r][5] += av * w1.y;
                acc[r][6] += av * w1.z; acc[r][7] += av * w1.w;
            }
        }
#pragma unroll
        for (int r = 0; r < 2; r++) a_cur[r] = a_nxt[r];
    }

#pragma unroll
    for (int r = 0; r < 2; r++) {
        const int lrow = rg * 2 + r;
        float4 v0, v1;
        v0.x = fmaxf(acc[r][0], 0.0f); v0.y = fmaxf(acc[r][1], 0.0f);
        v0.z = fmaxf(acc[r][2], 0.0f); v0.w = fmaxf(acc[r][3], 0.0f);
        v1.x = fmaxf(acc[r][4], 0.0f); v1.y = fmaxf(acc[r][5], 0.0f);
        v1.z = fmaxf(acc[r][6], 0.0f); v1.w = fmaxf(acc[r][7], 0.0f);
        *(float4*)(Hs + lrow * 68 + c0a) = v0;
        *(float4*)(Hs + lrow * 68 + c0b) = v1;
    }

    {
        const float4 v0 = *(const float4*)(B2 + c0a);
        const float4 v1 = *(const float4*)(B2 + c0b);
#pragma unroll
        for (int r = 0; r < 2; r++) {
            acc[r][0] = v0.x; acc[r][1] = v0.y; acc[r][2] = v0.z; acc[r][3] = v0.w;
            acc[r][4] = v1.x; acc[r][5] = v1.y; acc[r][6] = v1.z; acc[r][7] = v1.w;
        }
    }
    __syncthreads();

#pragma unroll 2
    for (int k4 = 0; k4 < 64; k4 += 4) {
        float4 a[2];
#pragma unroll
        for (int r = 0; r < 2; r++) a[r] = *(const float4*)(Hs + (rg * 2 + r) * 68 + k4);
#pragma unroll
        for (int kk = 0; kk < 4; kk++) {
            const float4 w0 = *(const float4*)(W2s + (k4 + kk) * 64 + c0a);
            const float4 w1 = *(const float4*)(W2s + (k4 + kk) * 64 + c0b);
#pragma unroll
            for (int r = 0; r < 2; r++) {
                float av = (kk == 0) ? a[r].x : (kk == 1) ? a[r].y
                         : (kk == 2) ? a[r].z : a[r].w;
                acc[r][0] += av * w0.x; acc[r][1] += av * w0.y;
                acc[r][2] += av * w0.z; acc[r][3] += av * w0.w;
                acc[r][4] += av * w1.x; acc[r][5] += av * w1.y;
                acc[r][6] += av * w1.z; acc[r][7] += av * w1.w;
            }
        }
    }

#pragma unroll
    for (int r = 0; r < 2; r++) {
        int rr = rbase + r;
        if (rr < rows) {
            float4 v0, v1;
            v0.x = fmaxf(acc[r][0], 0.0f); v0.y = fmaxf(acc[r][1], 0.0f);
            v0.z = fmaxf(acc[r][2], 0.0f); v0.w = fmaxf(acc[r][3], 0.0f);
            v1.x = fmaxf(acc[r][4], 0.0f); v1.y = fmaxf(acc[r][5], 0.0f);
            v1.z = fmaxf(acc[r][6], 0.0f); v1.w = fmaxf(acc[r][7], 0.0f);
            *(float4*)(Y + (size_t)rr * 64 + c0a) = v0;
            *(float4*)(Y + (size_t)rr * 64 + c0b) = v1;
        }
    }
}

// ---------------- n2a GEMM fused with graph pooling ----------------
// gsum[g] += sum over rows of graph g of relu(X[row]@W + B).  No H2 buffer.
__global__ __launch_bounds__(256) void gemm_pool(const float* __restrict__ X,
                                                 const float* __restrict__ W,
                                                 const float* __restrict__ Bv,
                                                 const int* __restrict__ batch,
                                                 float* __restrict__ gsum,
                                                 int rows) {
    constexpr int K = 64, C = 128;
    constexpr int CPT = 8, RPT = 4, COLG = 16;
    constexpr int BR = 64;

    __shared__ float Bs[K * C];        // 32 KB
    __shared__ float pool[8 * C];      // 4 KB

    const int cg = threadIdx.x % COLG;
    const int rg = threadIdx.x / COLG;
    const int c0a = cg * 4;
    const int c0b = 64 + cg * 4;
    const int rbase = blockIdx.x * BR + rg * RPT;

    {
        const float4* wsrc = (const float4*)W;
        float4* wdst = (float4*)Bs;
        for (int i = threadIdx.x; i < K * C / 4; i += 256) wdst[i] = wsrc[i];
    }
    for (int i = threadIdx.x; i < 8 * C; i += 256) pool[i] = 0.0f;

    int r0 = blockIdx.x * BR; if (r0 > rows - 1) r0 = rows - 1;
    int r1 = blockIdx.x * BR + BR - 1; if (r1 > rows - 1) r1 = rows - 1;
    const int gfirst = batch[r0];
    const int glast  = batch[r1];
    const int span = glast - gfirst + 1;
    const bool useLds = (span <= 8);

    const float* xptr[RPT];
    int gid[RPT];
#pragma unroll
    for (int r = 0; r < RPT; r++) {
        int rr = rbase + r;
        int ri = (rr < rows) ? rr : (rows - 1);
        xptr[r] = X + (size_t)ri * K;
        gid[r] = batch[ri];
    }

    float acc[RPT][CPT];
    {
        const float4 v0 = *(const float4*)(Bv + c0a);
        const float4 v1 = *(const float4*)(Bv + c0b);
#pragma unroll
        for (int r = 0; r < RPT; r++) {
            acc[r][0] = v0.x; acc[r][1] = v0.y; acc[r][2] = v0.z; acc[r][3] = v0.w;
            acc[r][4] = v1.x; acc[r][5] = v1.y; acc[r][6] = v1.z; acc[r][7] = v1.w;
        }
    }

    float4 a_cur[RPT], a_nxt[RPT];
#pragma unroll
    for (int r = 0; r < RPT; r++) a_cur[r] = *(const float4*)(xptr[r]);

    __syncthreads();   // Bs staged, pool zeroed

#pragma unroll 2
    for (int k4 = 0; k4 < K; k4 += 4) {
        if (k4 + 4 < K) {
#pragma unroll
            for (int r = 0; r < RPT; r++) a_nxt[r] = *(const float4*)(xptr[r] + k4 + 4);
        }
#pragma unroll
        for (int kk = 0; kk < 4; kk++) {
            const float4 w0 = *(const float4*)(Bs + (k4 + kk) * C + c0a);
            const float4 w1 = *(const float4*)(Bs + (k4 + kk) * C + c0b);
#pragma unroll
            for (int r = 0; r < RPT; r++) {
                float av = (kk == 0) ? a_cur[r].x : (kk == 1) ? a_cur[r].y
                         : (kk == 2) ? a_cur[r].z : a_cur[r].w;
                acc[r][0] += av * w0.x; acc[r][1] += av * w0.y;
                acc[r][2] += av * w0.z; acc[r][3] += av * w0.w;
                acc[r][4] += av * w1.x; acc[r][5] += av * w1.y;
                acc[r][6] += av * w1.z; acc[r][7] += av * w1.w;
            }
        }
#pragma unroll
        for (int r = 0; r < RPT; r++) a_cur[r] = a_nxt[r];
    }

    // ---- register run-reduction over this thread's 4 consecutive rows ----
    float part[CPT];
    int curg = -1;
#pragma unroll 1
    for (int r = 0; r < RPT; r++) {
        int rr = rbase + r;
        if (rr >= rows) break;
        int g = gid[r];
        if (g != curg) {
            if (curg >= 0) {
                float* p = useLds ? (pool + (curg - gfirst) * C)
                                  : (gsum + (size_t)curg * C);
#pragma unroll
                for (int j = 0; j < 4; j++) atomicAdd(p + c0a + j, part[j]);
#pragma unroll
                for (int j = 0; j < 4; j++) atomicAdd(p + c0b + j, part[4 + j]);
            }
            curg = g;
#pragma unroll
            for (int j = 0; j < CPT; j++) part[j] = 0.0f;
        }
#pragma unroll
        for (int j = 0; j < CPT; j++) part[j] += fmaxf(acc[r][j], 0.0f);
    }
    if (curg >= 0) {
        float* p = useLds ? (pool + (curg - gfirst) * C)
                          : (gsum + (size_t)curg * C);
#pragma unroll
        for (int j = 0; j < 4; j++) atomicAdd(p + c0a + j, part[j]);
#pragma unroll
        for (int j = 0; j < 4; j++) atomicAdd(p + c0b + j, part[4 + j]);
    }

    if (useLds) {
        __syncthreads();
        for (int i = threadIdx.x; i < span * C; i += 256) {
            float v = pool[i];
            if (v != 0.0f)
                atomicAdd(gsum + (size_t)(gfirst + (i >> 7)) * C + (i & 127), v);
        }
    }
}

// ---------------- head: m = gsum/cnt, emb = m@W2+b2 (commuted), 5-layer MLP ----
__global__ __launch_bounds__(128) void head_kernel(const float* __restrict__ gsum,
                                                   const int* __restrict__ se,
                                                   const float* __restrict__ usr,
                                                   const float* __restrict__ w2, const float* __restrict__ b2,
                                                   const float* __restrict__ h1w, const float* __restrict__ h1b,
                                                   const float* __restrict__ h2w, const float* __restrict__ h2b,
                                                   const float* __restrict__ h3w, const float* __restrict__ h3b,
                                                   const float* __restrict__ h4w, const float* __restrict__ h4b,
                                                   const float* __restrict__ h5w, const float* __restrict__ h5b,
                                                   float* __restrict__ out) {
    int g = blockIdx.x;
    int c = threadIdx.x;
    __shared__ float m[128];
    __shared__ float z0[140];
    __shared__ float z1[128];
    __shared__ float z2[64];
    __shared__ float z3[32];
    __shared__ float z4[16];

    int s = se[g], e = se[GG + g];
    float cnt = fmaxf((float)(e - s), 1.0f);
    m[c] = gsum[(size_t)g * 128 + c] / cnt;
    __syncthreads();

    {
        float acc = b2[c];
        for (int k = 0; k < 128; k++) acc += m[k] * w2[k * 128 + c];
        z0[c] = (e > s) ? acc : 0.0f;
    }
    if (c < 12) z0[128 + c] = usr[g * 12 + c];
    __syncthreads();

    {
        float acc = h1b[c];
        for (int k = 0; k < 140; k++) acc += z0[k] * h1w[k * 128 + c];
        z1[c] = fmaxf(acc, 0.0f);
    }
    __syncthreads();
    if (c < 64) {
        float acc = h2b[c];
        for (int k = 0; k < 128; k++) acc += z1[k] * h2w[k * 64 + c];
        z2[c] = fmaxf(acc, 0.0f);
    }
    __syncthreads();
    if (c < 32) {
        float acc = h3b[c];
        for (int k = 0; k < 64; k++) acc += z2[k] * h3w[k * 32 + c];
        z3[c] = fmaxf(acc, 0.0f);
    }
    __syncthreads();
    if (c < 16) {
        float acc = h4b[c];
        for (int k = 0; k < 32; k++) acc += z3[k] * h4w[k * 16 + c];
        z4[c] = fmaxf(acc, 0.0f);
    }
    __syncthreads();
    if (c == 0) {
        float acc = h5b[0];
        for (int k = 0; k < 16; k++) acc += z4[k] * h5w[k];
        out[g] = acc;
    }
}

extern "C" void kernel_launch(void* const* d_in, const int* in_sizes, int n_in,
                              void* d_out, int out_size, void* d_ws, size_t ws_size,
                              hipStream_t stream) {
    const float* x    = (const float*)d_in[0];
    const int*   ei   = (const int*)d_in[1];
    const float* ea   = (const float*)d_in[2];
    const int*   batch= (const int*)d_in[3];
    const float* usr  = (const float*)d_in[4];
    const float* e1w  = (const float*)d_in[5],  *e1b  = (const float*)d_in[6];
    const float* n1w1 = (const float*)d_in[7],  *n1b1 = (const float*)d_in[8];
    const float* n1w2 = (const float*)d_in[9],  *n1b2 = (const float*)d_in[10];
    const float* e2w  = (const float*)d_in[11], *e2b  = (const float*)d_in[12];
    const float* n2w1 = (const float*)d_in[13], *n2b1 = (const float*)d_in[14];
    const float* n2w2 = (const float*)d_in[15], *n2b2 = (const float*)d_in[16];
    const float* h1w  = (const float*)d_in[17], *h1b  = (const float*)d_in[18];
    const float* h2w  = (const float*)d_in[19], *h2b  = (const float*)d_in[20];
    const float* h3w  = (const float*)d_in[21], *h3b  = (const float*)d_in[22];
    const float* h4w  = (const float*)d_in[23], *h4b  = (const float*)d_in[24];
    const float* h5w  = (const float*)d_in[25], *h5b  = (const float*)d_in[26];

    float* w    = (float*)d_ws;
    float* agg  = w + AGG_OFF;
    float* h1   = w + H1_OFF;
    int*   se   = (int*)(w + SE_OFF);
    float* gsum = w + GSUM_OFF;

    int*   rowptr   = (int*)(w + CSR_OFF);
    int*   cursor   = rowptr + NN;
    int*   eidx     = cursor + NN;
    int*   esrc     = eidx + EE;
    int*   partials = esrc + EE;
    float* eaperm   = (float*)(partials + 256);

    hipMemsetAsync(se, 0, (size_t)GG * 2 * sizeof(int), stream);
    hipMemsetAsync(cursor, 0, (size_t)NN * sizeof(int), stream);
    hipMemsetAsync(gsum, 0, (size_t)GG * 128 * sizeof(float), stream);

    bounds_kernel<<<(NN + 255) / 256, 256, 0, stream>>>(batch, se);

    // ---- CSR build + slot-order edge materialization (shared by both layers) ----
    deg_kernel<<<(EE + 255) / 256, 256, 0, stream>>>(ei, cursor);
    scan1_kernel<<<NB1, 256, 0, stream>>>(cursor, rowptr, partials);
    scan2_kernel<<<1, 256, 0, stream>>>(partials);
    scan3_kernel<<<NB1, 256, 0, stream>>>(rowptr, partials);
    hipMemsetAsync(cursor, 0, (size_t)NN * sizeof(int), stream);
    scatter_kernel<<<(EE + 255) / 256, 256, 0, stream>>>(ei, rowptr, cursor, eidx, esrc);
    permute_kernel<<<(EE + 15) / 16, 256, 0, stream>>>(ea, eidx, eaperm);

    // ---- layer 1 ----
    agg_pass<<<(NN + 3) / 4, 256, 0, stream>>>(x, eaperm, esrc, e1w, e1b, rowptr, cursor, agg);
    node1_fused<<<(NN + 63) / 64, 256, 0, stream>>>(agg, n1w1, n1b1, n1w2, n1b2, h1, NN);

    // ---- layer 2 ----
    agg_pass<<<(NN + 3) / 4, 256, 0, stream>>>(h1, eaperm, esrc, e2w, e2b, rowptr, cursor, agg);
    gemm_pool<<<(NN + 63) / 64, 256, 0, stream>>>(agg, n2w1, n2b1, batch, gsum, NN);

    // ---- head ----
    head_kernel<<<GG, 128, 0, stream>>>(gsum, se, usr, n2w2, n2b2,
                                        h1w, h1b, h2w, h2b, h3w, h3b, h4w, h4b, h5w, h5b,
                                        (float*)d_out);
}